// Round 1
// 1598.074 us; speedup vs baseline: 1.0000x; 1.0000x over previous
//
#include <hip/hip_runtime.h>

#define INFV 1e30f

typedef __attribute__((ext_vector_type(8))) short bf16x8;
typedef __attribute__((ext_vector_type(16))) float f32x16;

__device__ __forceinline__ unsigned short f2bf(float f){
  union { float f; unsigned u; } v; v.f = f;
  unsigned r = v.u + 0x7FFFu + ((v.u >> 16) & 1u);
  return (unsigned short)(r >> 16);
}
__device__ __forceinline__ float bf2f(unsigned short b){
  union { unsigned u; float f; } v; v.u = ((unsigned)b) << 16;
  return v.f;
}
__device__ __forceinline__ void async_cp16(void* lds, const void* g){
  __builtin_amdgcn_global_load_lds((const __attribute__((address_space(1))) unsigned int*)g,
                                   (__attribute__((address_space(3))) unsigned int*)lds,
                                   16, 0, 0);
}

// ---------------- pooling: 3x3 avg (zero-pad, /9) ----------------
__global__ void k_pool(const float* __restrict__ f2, const float* __restrict__ f3,
                       float* __restrict__ pf2, float* __restrict__ pf3){
  const int idx = blockIdx.x*256 + threadIdx.x;
  if (idx < 512*784){
    const int c = idx / 784, rem = idx % 784, y = rem / 28, x = rem % 28;
    const float* base = f2 + c*784;
    float s = 0.f;
    for (int dy = -1; dy <= 1; ++dy){
      int yy = y + dy; if (yy < 0 || yy > 27) continue;
      for (int dx = -1; dx <= 1; ++dx){
        int xx = x + dx; if (xx < 0 || xx > 27) continue;
        s += base[yy*28 + xx];
      }
    }
    pf2[idx] = s * (1.0f/9.0f);
  } else {
    const int j = idx - 512*784;
    if (j < 1024*196){
      const int c = j / 196, rem = j % 196, y = rem / 14, x = rem % 14;
      const float* base = f3 + c*196;
      float s = 0.f;
      for (int dy = -1; dy <= 1; ++dy){
        int yy = y + dy; if (yy < 0 || yy > 13) continue;
        for (int dx = -1; dx <= 1; ++dx){
          int xx = x + dx; if (xx < 0 || xx > 13) continue;
          s += base[yy*14 + xx];
        }
      }
      pf3[j] = s * (1.0f/9.0f);
    }
  }
}

// ---------------- build bf16 embedding in swizzled A layout + ||e||^2 ----------------
// A layout: chunk c (=k/32) of 26624 shorts: slot = ((k>>3)&3)*832 + p, 8 bf16 per slot.
__global__ void k_emb(const float* __restrict__ pf2, const float* __restrict__ pf3,
                      unsigned short* __restrict__ Aw, float* __restrict__ en2){
  __shared__ float red[256];
  const int p = blockIdx.x;     // 0..831 (784..831 are zero pad rows)
  const int t = threadIdx.x;
  const int y = p / 28, x = p % 28;
  float a2 = 0.f;
  for (int it = 0; it < 6; ++it){
    const int k = it*256 + t;
    float v = 0.f;
    if (p < 784){
      if (k < 512) v = pf2[k*784 + y*28 + x];
      else         v = pf3[(k - 512)*196 + (y >> 1)*14 + (x >> 1)];
    }
    a2 += v*v;
    const int chunk = k >> 5, kq = (k >> 3) & 3, j = k & 7;
    Aw[(size_t)chunk*26624 + (size_t)(kq*832 + p)*8 + j] = f2bf(v);
  }
  red[t] = a2;
  __syncthreads();
  for (int s = 128; s > 0; s >>= 1){
    if (t < s) red[t] += red[t + s];
    __syncthreads();
  }
  if (t == 0) en2[p] = red[0];
}

// ---------------- main fused distance GEMM + per-row partial min ----------------
// block: 768 threads = 12 waves. waves 0,1 have 3 m-tiles (incl rows 768..831), others 2.
// per wave: rm m-tiles(32) x 2 n-tiles(32), mfma_f32_32x32x16_bf16, K=1536 in 48 rounds of 32.
// 2-phase pipeline: stage chunk r+1 (A bf16 + B fp32, both via global_load_lds) is issued
// BEFORE compute of chunk r; the __syncthreads after compute drains vmcnt, hiding the
// staging latency under the MFMA phase. B fp32->bf16 convert (+ exact fp32 ||b||^2)
// happens in a short phase between two barriers (zero extra register pressure).
__global__ __launch_bounds__(768, 3) void k_gemm(const float* __restrict__ bank,
                                                 const unsigned short* __restrict__ Aw,
                                                 const float* __restrict__ en2,
                                                 float* __restrict__ pmin){
  __shared__ short As[2][26624];  // 104 KB: dbuf [kq 0..3][row 0..831][8 bf16]
  __shared__ short Bs[2][2048];   // 8 KB:   dbuf [kq 0..3][n 0..63][8 bf16]
  __shared__ float Bf[2][2048];   // 16 KB:  dbuf fp32 B staging [row 0..63][k 0..31]
  __shared__ float en2s[832];
  __shared__ float bn2p[512];
  __shared__ float bn2v[64];

  const int tid = threadIdx.x;
  const int w = tid >> 6;
  const int lane = tid & 63;
  const int hi = lane >> 5;
  const int ln = lane & 31;
  const int n0 = blockIdx.x * 64;
  const int rm = (w < 2) ? 3 : 2;

  for (int i = tid; i < 832; i += 768) en2s[i] = en2[i];

  f32x16 acc[3][2];
  #pragma unroll
  for (int i = 0; i < 3; ++i)
    #pragma unroll
    for (int j = 0; j < 2; ++j)
      #pragma unroll
      for (int g = 0; g < 16; ++g) acc[i][j][g] = 0.0f;

  // B staging roles (threads 0..511): 64 rows x 8 parts of 4 fp32
  const int brow = tid >> 3;
  const int bpart = tid & 7;
  const bool bth = (tid < 512);
  const bool bvalid = bth && (n0 + brow < 100000);
  const float* bp = bank + (size_t)(n0 + brow) * 1536 + bpart * 4;
  const int bslot = ((bpart >> 1) * 64 + brow) * 8 + (bpart & 1) * 4;
  float s2 = 0.0f;

  const int row0 = w*64 + ln;
  const int row2 = 768 + w*32 + ln;  // only valid for w<2

  // ---- prologue: stage chunk 0 ----
  if (bvalid) async_cp16(&Bf[0][tid*4], bp);
  {
    const unsigned short* Ag = Aw;
    #pragma unroll
    for (int it = 0; it < 5; ++it){
      int u = it*768 + tid;
      if (u < 3328) async_cp16(&As[0][u*8], Ag + (size_t)u*8);
    }
  }
  __syncthreads();                       // chunk-0 staging complete
  if (bth){
    float4 bv = make_float4(0.f, 0.f, 0.f, 0.f);
    if (bvalid) bv = *(const float4*)&Bf[0][tid*4];
    s2 += bv.x*bv.x + bv.y*bv.y + bv.z*bv.z + bv.w*bv.w;
    short4 sv;
    sv.x = (short)f2bf(bv.x); sv.y = (short)f2bf(bv.y);
    sv.z = (short)f2bf(bv.z); sv.w = (short)f2bf(bv.w);
    *(short4*)&Bs[0][bslot] = sv;
  }
  __syncthreads();                       // Bs[0] visible

  int cur = 0;
  for (int r = 0; r < 48; ++r){
    const int nxt = cur ^ 1;
    // ---- issue stage of chunk r+1 (HBM B first: longest latency) ----
    if (r < 47){
      if (bvalid) async_cp16(&Bf[nxt][tid*4], bp + (r+1)*32);
      const unsigned short* Ag = Aw + (size_t)(r+1) * 26624;
      #pragma unroll
      for (int it = 0; it < 5; ++it){
        int u = it*768 + tid;
        if (u < 3328) async_cp16(&As[nxt][u*8], Ag + (size_t)u*8);
      }
    }
    // ---- compute on chunk r (overlaps with in-flight staging) ----
    const short* Ac = As[cur];
    const short* Bc = Bs[cur];
    #pragma unroll
    for (int s = 0; s < 2; ++s){
      const int kq = s*2 + hi;
      bf16x8 b0 = *(const bf16x8*)&Bc[(kq*64 + ln)*8];
      bf16x8 b1 = *(const bf16x8*)&Bc[(kq*64 + 32 + ln)*8];
      #pragma unroll
      for (int i = 0; i < 3; ++i){
        if (i < rm){
          const int rr = (i < 2) ? (row0 + i*32) : row2;
          bf16x8 a = *(const bf16x8*)&Ac[(kq*832 + rr)*8];
          acc[i][0] = __builtin_amdgcn_mfma_f32_32x32x16_bf16(a, b0, acc[i][0], 0, 0, 0);
          acc[i][1] = __builtin_amdgcn_mfma_f32_32x32x16_bf16(a, b1, acc[i][1], 0, 0, 0);
        }
      }
    }
    __syncthreads();                     // drains vmcnt: As[nxt]/Bf[nxt] landed; all waves done with cur
    // ---- short convert phase: Bf[nxt] fp32 -> Bs[nxt] bf16, ||b||^2 in exact fp32 ----
    if (r < 47 && bth){
      float4 bv = make_float4(0.f, 0.f, 0.f, 0.f);
      if (bvalid) bv = *(const float4*)&Bf[nxt][tid*4];
      s2 += bv.x*bv.x + bv.y*bv.y + bv.z*bv.z + bv.w*bv.w;
      short4 sv;
      sv.x = (short)f2bf(bv.x); sv.y = (short)f2bf(bv.y);
      sv.z = (short)f2bf(bv.z); sv.w = (short)f2bf(bv.w);
      *(short4*)&Bs[nxt][bslot] = sv;
    }
    __syncthreads();                     // Bs[nxt] visible
    cur = nxt;
  }

  // finalize ||b||^2
  if (bth) bn2p[tid] = s2;
  __syncthreads();
  if (tid < 64){
    float t0 = 0.f;
    #pragma unroll
    for (int j = 0; j < 8; ++j) t0 += bn2p[tid*8 + j];
    bn2v[tid] = (n0 + tid < 100000) ? t0 : INFV;
  }
  __syncthreads();

  // epilogue: d2 = ||e||^2 + ||b||^2 - 2 dot ; min over this block's 64 n per row
  #pragma unroll
  for (int i = 0; i < 3; ++i){
    if (i < rm){
      const int mb = (i < 2) ? (w*64 + i*32) : (768 + w*32);
      float vv[16];
      #pragma unroll
      for (int g = 0; g < 16; ++g){
        const int m = mb + (g & 3) + 8*(g >> 2) + 4*hi;
        const float e2 = en2s[m];
        float d0 = e2 + bn2v[ln]      - 2.0f*acc[i][0][g];
        float d1 = e2 + bn2v[32 + ln] - 2.0f*acc[i][1][g];
        float v = fminf(d0, d1);
        #pragma unroll
        for (int off = 1; off < 32; off <<= 1)
          v = fminf(v, __shfl_xor(v, off, 64));
        vv[g] = v;
      }
      if (ln == 0){
        #pragma unroll
        for (int g = 0; g < 16; ++g){
          const int m = mb + (g & 3) + 8*(g >> 2) + 4*hi;
          pmin[(size_t)blockIdx.x * 832 + m] = vv[g];
        }
      }
    }
  }
}

// ---------------- reduce partial mins -> col0 = sqrt(clip(min)) ----------------
__global__ void k_colmin(const float* __restrict__ pmin, float* __restrict__ col0){
  __shared__ float red[256];
  const int t = threadIdx.x;
  const int m0 = blockIdx.x * 64;
  const int m = m0 + (t & 63);
  const int g = t >> 6;
  float v = INFV;
  for (int b = g; b < 1563; b += 4) v = fminf(v, pmin[(size_t)b*832 + m]);
  red[t] = v;
  __syncthreads();
  if (t < 64){
    float vv = fminf(fminf(red[t], red[64+t]), fminf(red[128+t], red[192+t]));
    col0[m0 + t] = sqrtf(fmaxf(vv, 1e-12f));
  }
}

// ---------------- argmax row (first index) + 9th-smallest block-min threshold ----------------
__global__ void k_argmax(const float* __restrict__ col0,
                         const float* __restrict__ pmin,
                         float* __restrict__ scal){
  __shared__ float red[256];
  __shared__ int redi[256];
  __shared__ float cand[1563];
  const int t = threadIdx.x;

  float best = -INFV; int bi = 0x7FFFFFFF;
  for (int m = t; m < 784; m += 256){
    float v = col0[m];
    if (v > best){ best = v; bi = m; }
  }
  red[t] = best; redi[t] = bi;
  __syncthreads();
  for (int s = 128; s > 0; s >>= 1){
    if (t < s){
      if (red[t+s] > red[t] || (red[t+s] == red[t] && redi[t+s] < redi[t])){
        red[t] = red[t+s]; redi[t] = redi[t+s];
      }
    }
    __syncthreads();
  }
  const int r = redi[0];
  const float maxv = red[0];
  __syncthreads();

  for (int b = t; b < 1563; b += 256) cand[b] = pmin[(size_t)b*832 + r];
  __syncthreads();

  float b9 = 0.f;
  for (int it = 0; it < 9; ++it){
    float lb = INFV; int li = -1;
    for (int b = t; b < 1563; b += 256){
      float v = cand[b];
      if (v < lb){ lb = v; li = b; }
    }
    red[t] = lb; redi[t] = li;
    __syncthreads();
    for (int s = 128; s > 0; s >>= 1){
      if (t < s && red[t+s] < red[t]){ red[t] = red[t+s]; redi[t] = redi[t+s]; }
      __syncthreads();
    }
    b9 = red[0];
    if (t == 0 && redi[0] >= 0) cand[redi[0]] = INFV;
    __syncthreads();
  }
  if (t == 0){
    ((int*)scal)[0] = r;
    scal[1] = maxv;
    scal[2] = b9 + 1.0f;   // margin >> bf16-dot error bound
  }
}

// ---------------- recompute candidate blocks' distances for row r ----------------
__global__ void k_cand(const float* __restrict__ bank,
                       const unsigned short* __restrict__ Aw,
                       const float* __restrict__ en2,
                       const float* __restrict__ pmin,
                       const float* __restrict__ scal,
                       float* __restrict__ d2row){
  const int bid = blockIdx.x;
  const int t = threadIdx.x;
  const int r = ((const int*)scal)[0];
  const float thr = scal[2];
  const int n0 = bid * 64;

  if (pmin[(size_t)bid*832 + r] > thr){
    if (t < 64) d2row[n0 + t] = INFV;
    return;
  }
  __shared__ short er[1536];
  for (int k = t; k < 1536; k += 256){
    const int chunk = k >> 5, kq = (k >> 3) & 3, j = k & 7;
    er[k] = Aw[(size_t)chunk*26624 + (size_t)(kq*832 + r)*8 + j];
  }
  __syncthreads();
  const float e2r = en2[r];
  const int wv = t >> 6, ln = t & 63;
  for (int i = 0; i < 16; ++i){
    const int nl = wv*16 + i;
    const int n = n0 + nl;
    float dot = 0.f, b2 = 0.f;
    if (n < 100000){
      const float* bp2 = bank + (size_t)n * 1536;
      for (int k = ln; k < 1536; k += 64){
        float b = bp2[k];
        b2 += b*b;
        dot += bf2f(er[k]) * bf2f(f2bf(b));   // match pass-1 rounding
      }
    }
    #pragma unroll
    for (int off = 1; off < 64; off <<= 1){
      dot += __shfl_xor(dot, off, 64);
      b2  += __shfl_xor(b2,  off, 64);
    }
    if (ln == 0) d2row[n] = (n < 100000) ? (e2r + b2 - 2.0f*dot) : INFV;
  }
}

// ---------------- top-9 of d2row -> softmax weight -> score ----------------
__global__ void k_score(const float* __restrict__ d2row,
                        const float* __restrict__ scal,
                        float* __restrict__ outs){
  __shared__ float cs[2304];
  __shared__ float red[256];
  __shared__ int redi[256];
  __shared__ float nine[9];
  const int t = threadIdx.x;
  float loc[9];
  #pragma unroll
  for (int q = 0; q < 9; ++q) loc[q] = INFV;
  for (int n = t; n < 100000; n += 256){
    float v = d2row[n];
    if (v < loc[8]){
      loc[8] = v;
      #pragma unroll
      for (int q = 8; q > 0; --q){
        float a = fminf(loc[q-1], loc[q]);
        float b = fmaxf(loc[q-1], loc[q]);
        loc[q-1] = a; loc[q] = b;
      }
    }
  }
  #pragma unroll
  for (int q = 0; q < 9; ++q) cs[t*9 + q] = loc[q];
  __syncthreads();
  for (int it = 0; it < 9; ++it){
    float lb = INFV; int li = -1;
    for (int jx = t; jx < 2304; jx += 256){
      float v = cs[jx];
      if (v < lb){ lb = v; li = jx; }
    }
    red[t] = lb; redi[t] = li;
    __syncthreads();
    for (int s = 128; s > 0; s >>= 1){
      if (t < s && red[t+s] < red[t]){ red[t] = red[t+s]; redi[t] = redi[t+s]; }
      __syncthreads();
    }
    if (t == 0){ nine[it] = red[0]; if (redi[0] >= 0) cs[redi[0]] = INFV; }
    __syncthreads();
  }
  if (t == 0){
    float s[9];
    #pragma unroll
    for (int q = 0; q < 9; ++q) s[q] = sqrtf(fmaxf(nine[q], 1e-12f));
    const float mx = s[8];          // largest of the 9 scores
    float sum = 0.f;
    #pragma unroll
    for (int q = 0; q < 9; ++q) sum += expf(s[q] - mx);
    const float weight = 1.0f - 1.0f/sum;   // 1 - max(e)/sum(e), overflow-safe
    outs[0] = weight * scal[1];
  }
}

// ---------------- bilinear 28->224 (half-pixel, edge clamp) + vertical gaussian ----------------
__global__ void k_vblur(const float* __restrict__ col0, float* __restrict__ vmap){
  __shared__ float am[784];
  __shared__ float kw[33];
  const int t = threadIdx.x;
  for (int q = t; q < 784; q += 256) am[q] = col0[q];
  if (t < 33){ float d = (float)t - 16.0f; kw[t] = expf(-d*d*(1.0f/32.0f)); }
  __syncthreads();
  if (t == 0){
    float ss = 0.f;
    for (int q = 0; q < 33; ++q) ss += kw[q];
    const float inv = 1.0f/ss;
    for (int q = 0; q < 33; ++q) kw[q] *= inv;
  }
  __syncthreads();
  const int id = blockIdx.x*256 + t;
  const int i = id / 224, j = id % 224;
  const float ux = (j + 0.5f)*0.125f - 0.5f;
  const float fx0 = floorf(ux);
  const float fx = ux - fx0;
  int x0 = (int)fx0; int x1 = x0 + 1;
  x0 = max(0, min(27, x0)); x1 = max(0, min(27, x1));
  float a = 0.f;
  for (int d = 0; d < 33; ++d){
    int ii = i + d - 16;                         // symmetric pad
    ii = (ii < 0) ? (-1 - ii) : ((ii > 223) ? (447 - ii) : ii);
    const float uy = (ii + 0.5f)*0.125f - 0.5f;
    const float fy0 = floorf(uy);
    const float fy = uy - fy0;
    int y0 = (int)fy0; int y1 = y0 + 1;
    y0 = max(0, min(27, y0)); y1 = max(0, min(27, y1));
    const float top = (1.0f - fx)*am[y0*28 + x0] + fx*am[y0*28 + x1];
    const float bot = (1.0f - fx)*am[y1*28 + x0] + fx*am[y1*28 + x1];
    a += kw[d]*((1.0f - fy)*top + fy*bot);
  }
  vmap[id] = a;
}

// ---------------- horizontal gaussian (symmetric pad) ----------------
__global__ void k_hblur(const float* __restrict__ vmap, float* __restrict__ outm){
  __shared__ float rowb[256];
  __shared__ float kw[33];
  const int i = blockIdx.x;
  const int t = threadIdx.x;
  if (t < 33){ float d = (float)t - 16.0f; kw[t] = expf(-d*d*(1.0f/32.0f)); }
  __syncthreads();
  if (t == 0){
    float ss = 0.f;
    for (int q = 0; q < 33; ++q) ss += kw[q];
    const float inv = 1.0f/ss;
    for (int q = 0; q < 33; ++q) kw[q] *= inv;
  }
  int c = t - 16;
  c = (c < 0) ? (-1 - c) : ((c > 223) ? (447 - c) : c);
  rowb[t] = vmap[i*224 + c];
  __syncthreads();
  if (t < 224){
    float a = 0.f;
    #pragma unroll
    for (int d = 0; d < 33; ++d) a += kw[d]*rowb[t + d];
    outm[i*224 + t] = a;
  }
}

extern "C" void kernel_launch(void* const* d_in, const int* in_sizes, int n_in,
                              void* d_out, int out_size, void* d_ws, size_t ws_size,
                              hipStream_t stream) {
  const float* f2   = (const float*)d_in[0];   // 1x512x28x28
  const float* f3   = (const float*)d_in[1];   // 1x1024x14x14
  const float* bank = (const float*)d_in[2];   // 100000x1536
  float* out = (float*)d_out;                  // 50176 map + 1 score

  char* ws = (char*)d_ws;
  size_t off = 0;
  auto alloc = [&](size_t bytes) -> void* {
    void* p = ws + off;
    off += (bytes + 255) & ~(size_t)255;
    return p;
  };
  float* pf2           = (float*)alloc((size_t)512*784*4);
  float* pf3           = (float*)alloc((size_t)1024*196*4);
  unsigned short* A_ws = (unsigned short*)alloc((size_t)48*26624*2);
  float* en2           = (float*)alloc(832*4);
  float* pmin          = (float*)alloc((size_t)1563*832*4);
  float* col0          = (float*)alloc(832*4);
  float* scal          = (float*)alloc(64);
  float* d2row         = (float*)alloc(100032*4);
  float* vmap          = (float*)alloc((size_t)50176*4);

  k_pool  <<<2352, 256, 0, stream>>>(f2, f3, pf2, pf3);
  k_emb   <<<832,  256, 0, stream>>>(pf2, pf3, A_ws, en2);
  k_gemm  <<<1563, 768, 0, stream>>>(bank, A_ws, en2, pmin);
  k_colmin<<<13,   256, 0, stream>>>(pmin, col0);
  k_argmax<<<1,    256, 0, stream>>>(col0, pmin, scal);
  k_cand  <<<1563, 256, 0, stream>>>(bank, A_ws, en2, pmin, scal, d2row);
  k_score <<<1,    256, 0, stream>>>(d2row, scal, out + 50176);
  k_vblur <<<196,  256, 0, stream>>>(col0, vmap);
  k_hblur <<<224,  256, 0, stream>>>(vmap, out);
}

// Round 2
// 1536.205 us; speedup vs baseline: 1.0403x; 1.0403x over previous
//
#include <hip/hip_runtime.h>

#define INFV 1e30f

typedef __attribute__((ext_vector_type(8))) short bf16x8;
typedef __attribute__((ext_vector_type(16))) float f32x16;

__device__ __forceinline__ unsigned short f2bf(float f){
  union { float f; unsigned u; } v; v.f = f;
  unsigned r = v.u + 0x7FFFu + ((v.u >> 16) & 1u);
  return (unsigned short)(r >> 16);
}
__device__ __forceinline__ float bf2f(unsigned short b){
  union { unsigned u; float f; } v; v.u = ((unsigned)b) << 16;
  return v.f;
}
__device__ __forceinline__ void async_cp16(void* lds, const void* g){
  __builtin_amdgcn_global_load_lds((const __attribute__((address_space(1))) unsigned int*)g,
                                   (__attribute__((address_space(3))) unsigned int*)lds,
                                   16, 0, 0);
}

// ---------------- pooling: 3x3 avg (zero-pad, /9) ----------------
__global__ void k_pool(const float* __restrict__ f2, const float* __restrict__ f3,
                       float* __restrict__ pf2, float* __restrict__ pf3){
  const int idx = blockIdx.x*256 + threadIdx.x;
  if (idx < 512*784){
    const int c = idx / 784, rem = idx % 784, y = rem / 28, x = rem % 28;
    const float* base = f2 + c*784;
    float s = 0.f;
    for (int dy = -1; dy <= 1; ++dy){
      int yy = y + dy; if (yy < 0 || yy > 27) continue;
      for (int dx = -1; dx <= 1; ++dx){
        int xx = x + dx; if (xx < 0 || xx > 27) continue;
        s += base[yy*28 + xx];
      }
    }
    pf2[idx] = s * (1.0f/9.0f);
  } else {
    const int j = idx - 512*784;
    if (j < 1024*196){
      const int c = j / 196, rem = j % 196, y = rem / 14, x = rem % 14;
      const float* base = f3 + c*196;
      float s = 0.f;
      for (int dy = -1; dy <= 1; ++dy){
        int yy = y + dy; if (yy < 0 || yy > 13) continue;
        for (int dx = -1; dx <= 1; ++dx){
          int xx = x + dx; if (xx < 0 || xx > 13) continue;
          s += base[yy*14 + xx];
        }
      }
      pf3[j] = s * (1.0f/9.0f);
    }
  }
}

// ---------------- build bf16 embedding in swizzled A layout + ||e||^2 ----------------
// A layout: chunk c (=k/32) of 26624 shorts: slot = ((k>>3)&3)*832 + p, 8 bf16 per slot.
__global__ void k_emb(const float* __restrict__ pf2, const float* __restrict__ pf3,
                      unsigned short* __restrict__ Aw, float* __restrict__ en2){
  __shared__ float red[256];
  const int p = blockIdx.x;     // 0..831 (784..831 are zero pad rows)
  const int t = threadIdx.x;
  const int y = p / 28, x = p % 28;
  float a2 = 0.f;
  for (int it = 0; it < 6; ++it){
    const int k = it*256 + t;
    float v = 0.f;
    if (p < 784){
      if (k < 512) v = pf2[k*784 + y*28 + x];
      else         v = pf3[(k - 512)*196 + (y >> 1)*14 + (x >> 1)];
    }
    a2 += v*v;
    const int chunk = k >> 5, kq = (k >> 3) & 3, j = k & 7;
    Aw[(size_t)chunk*26624 + (size_t)(kq*832 + p)*8 + j] = f2bf(v);
  }
  red[t] = a2;
  __syncthreads();
  for (int s = 128; s > 0; s >>= 1){
    if (t < s) red[t] += red[t + s];
    __syncthreads();
  }
  if (t == 0) en2[p] = red[0];
}

// ---------------- main fused distance GEMM + per-row partial min ----------------
// block: 768 threads = 12 waves. waves 0,1 have 3 m-tiles (incl rows 768..831), others 2.
// A fragments are NOT shared between waves -> loaded straight from global (L2-resident,
// 2.5 MB, coalesced 16B/lane) into VGPRs, software-pipelined per-wave:
//   load a1(chunk r,s=1) | MFMA s=0 with a0 | load a0(chunk r+1,s=0) | MFMA s=1 with a1.
// Only B (8 KB/chunk, shared by all waves) goes through LDS (global_load_lds fp32 ->
// convert bf16 + exact fp32 ||b||^2), double-buffered with 2 barriers/chunk.
__global__ __launch_bounds__(768, 3) void k_gemm(const float* __restrict__ bank,
                                                 const unsigned short* __restrict__ Aw,
                                                 const float* __restrict__ en2,
                                                 float* __restrict__ pmin){
  __shared__ short Bs[2][2048];   // 8 KB:  dbuf [kq 0..3][n 0..63][8 bf16]
  __shared__ float Bf[2][2048];   // 16 KB: dbuf fp32 B staging
  __shared__ float en2s[832];
  __shared__ float bn2p[512];
  __shared__ float bn2v[64];

  const int tid = threadIdx.x;
  const int w = tid >> 6;
  const int lane = tid & 63;
  const int hi = lane >> 5;
  const int ln = lane & 31;
  const int n0 = blockIdx.x * 64;
  const int rm = (w < 2) ? 3 : 2;

  for (int i = tid; i < 832; i += 768) en2s[i] = en2[i];

  f32x16 acc[3][2];
  #pragma unroll
  for (int i = 0; i < 3; ++i)
    #pragma unroll
    for (int j = 0; j < 2; ++j)
      #pragma unroll
      for (int g = 0; g < 16; ++g) acc[i][j][g] = 0.0f;

  // B staging roles (threads 0..511): 64 rows x 8 parts of 4 fp32
  const int brow = tid >> 3;
  const int bpart = tid & 7;
  const bool bth = (tid < 512);
  const bool bvalid = bth && (n0 + brow < 100000);
  const float* bp = bank + (size_t)(n0 + brow) * 1536 + bpart * 4;
  const int bslot = ((bpart >> 1) * 64 + brow) * 8 + (bpart & 1) * 4;
  float s2 = 0.0f;

  // A direct-load pointers (units: shorts). addr(i,s,r) = r*26624 + ((s*2+hi)*832 + rr_i)*8
  const int row0 = w*64 + ln;
  const int row2 = 768 + w*32 + ln;  // only valid for w<2
  const unsigned short* pA0 = Aw + (size_t)(hi*832 + row0)*8;
  const unsigned short* pA2 = Aw + (size_t)(hi*832 + row2)*8;

  bf16x8 a0[3], a1[3];

  // ---- prologue: stage B chunk 0, load A frags (chunk 0, s=0) ----
  if (bvalid) async_cp16(&Bf[0][tid*4], bp);
  a0[0] = *(const bf16x8*)(pA0);
  a0[1] = *(const bf16x8*)(pA0 + 256);
  if (rm == 3) a0[2] = *(const bf16x8*)(pA2);
  __syncthreads();                       // Bf[0] + a0 landed
  if (bth){
    float4 bv = make_float4(0.f, 0.f, 0.f, 0.f);
    if (bvalid) bv = *(const float4*)&Bf[0][tid*4];
    s2 += bv.x*bv.x + bv.y*bv.y + bv.z*bv.z + bv.w*bv.w;
    short4 sv;
    sv.x = (short)f2bf(bv.x); sv.y = (short)f2bf(bv.y);
    sv.z = (short)f2bf(bv.z); sv.w = (short)f2bf(bv.w);
    *(short4*)&Bs[0][bslot] = sv;
  }
  __syncthreads();                       // Bs[0] visible

  int cur = 0;
  size_t coff = 0;                       // chunk offset in shorts (r*26624)
  for (int r = 0; r < 48; ++r){
    const int nxt = cur ^ 1;
    // issue next-chunk B stage (HBM, longest latency) first
    if (r < 47){
      if (bvalid) async_cp16(&Bf[nxt][tid*4], bp + (r+1)*32);
    }
    // load A frags for this chunk, s=1 (overlaps s=0 MFMAs below)
    a1[0] = *(const bf16x8*)(pA0 + coff + 13312);
    a1[1] = *(const bf16x8*)(pA0 + coff + 13312 + 256);
    if (rm == 3) a1[2] = *(const bf16x8*)(pA2 + coff + 13312);
    // ---- compute s=0 (kq = hi) ----
    {
      bf16x8 b0 = *(const bf16x8*)&Bs[cur][(hi*64 + ln)*8];
      bf16x8 b1 = *(const bf16x8*)&Bs[cur][(hi*64 + 32 + ln)*8];
      acc[0][0] = __builtin_amdgcn_mfma_f32_32x32x16_bf16(a0[0], b0, acc[0][0], 0, 0, 0);
      acc[0][1] = __builtin_amdgcn_mfma_f32_32x32x16_bf16(a0[0], b1, acc[0][1], 0, 0, 0);
      acc[1][0] = __builtin_amdgcn_mfma_f32_32x32x16_bf16(a0[1], b0, acc[1][0], 0, 0, 0);
      acc[1][1] = __builtin_amdgcn_mfma_f32_32x32x16_bf16(a0[1], b1, acc[1][1], 0, 0, 0);
      if (rm == 3){
        acc[2][0] = __builtin_amdgcn_mfma_f32_32x32x16_bf16(a0[2], b0, acc[2][0], 0, 0, 0);
        acc[2][1] = __builtin_amdgcn_mfma_f32_32x32x16_bf16(a0[2], b1, acc[2][1], 0, 0, 0);
      }
    }
    // prefetch A frags for chunk r+1, s=0 (overlaps s=1 MFMAs below)
    if (r < 47){
      a0[0] = *(const bf16x8*)(pA0 + coff + 26624);
      a0[1] = *(const bf16x8*)(pA0 + coff + 26624 + 256);
      if (rm == 3) a0[2] = *(const bf16x8*)(pA2 + coff + 26624);
    }
    // ---- compute s=1 (kq = 2 + hi) ----
    {
      bf16x8 b0 = *(const bf16x8*)&Bs[cur][((2 + hi)*64 + ln)*8];
      bf16x8 b1 = *(const bf16x8*)&Bs[cur][((2 + hi)*64 + 32 + ln)*8];
      acc[0][0] = __builtin_amdgcn_mfma_f32_32x32x16_bf16(a1[0], b0, acc[0][0], 0, 0, 0);
      acc[0][1] = __builtin_amdgcn_mfma_f32_32x32x16_bf16(a1[0], b1, acc[0][1], 0, 0, 0);
      acc[1][0] = __builtin_amdgcn_mfma_f32_32x32x16_bf16(a1[1], b0, acc[1][0], 0, 0, 0);
      acc[1][1] = __builtin_amdgcn_mfma_f32_32x32x16_bf16(a1[1], b1, acc[1][1], 0, 0, 0);
      if (rm == 3){
        acc[2][0] = __builtin_amdgcn_mfma_f32_32x32x16_bf16(a1[2], b0, acc[2][0], 0, 0, 0);
        acc[2][1] = __builtin_amdgcn_mfma_f32_32x32x16_bf16(a1[2], b1, acc[2][1], 0, 0, 0);
      }
    }
    __syncthreads();                     // Bf[nxt] landed; all waves done reading Bs[cur]
    // ---- short convert phase: Bf[nxt] fp32 -> Bs[nxt] bf16, ||b||^2 in exact fp32 ----
    if (r < 47 && bth){
      float4 bv = make_float4(0.f, 0.f, 0.f, 0.f);
      if (bvalid) bv = *(const float4*)&Bf[nxt][tid*4];
      s2 += bv.x*bv.x + bv.y*bv.y + bv.z*bv.z + bv.w*bv.w;
      short4 sv;
      sv.x = (short)f2bf(bv.x); sv.y = (short)f2bf(bv.y);
      sv.z = (short)f2bf(bv.z); sv.w = (short)f2bf(bv.w);
      *(short4*)&Bs[nxt][bslot] = sv;
    }
    __syncthreads();                     // Bs[nxt] visible
    cur = nxt;
    coff += 26624;
  }

  // finalize ||b||^2
  if (bth) bn2p[tid] = s2;
  __syncthreads();
  if (tid < 64){
    float t0 = 0.f;
    #pragma unroll
    for (int j = 0; j < 8; ++j) t0 += bn2p[tid*8 + j];
    bn2v[tid] = (n0 + tid < 100000) ? t0 : INFV;
  }
  __syncthreads();

  // epilogue: d2 = ||e||^2 + ||b||^2 - 2 dot ; min over this block's 64 n per row
  #pragma unroll
  for (int i = 0; i < 3; ++i){
    if (i < rm){
      const int mb = (i < 2) ? (w*64 + i*32) : (768 + w*32);
      float vv[16];
      #pragma unroll
      for (int g = 0; g < 16; ++g){
        const int m = mb + (g & 3) + 8*(g >> 2) + 4*hi;
        const float e2 = en2s[m];
        float d0 = e2 + bn2v[ln]      - 2.0f*acc[i][0][g];
        float d1 = e2 + bn2v[32 + ln] - 2.0f*acc[i][1][g];
        float v = fminf(d0, d1);
        #pragma unroll
        for (int off = 1; off < 32; off <<= 1)
          v = fminf(v, __shfl_xor(v, off, 64));
        vv[g] = v;
      }
      if (ln == 0){
        #pragma unroll
        for (int g = 0; g < 16; ++g){
          const int m = mb + (g & 3) + 8*(g >> 2) + 4*hi;
          pmin[(size_t)blockIdx.x * 832 + m] = vv[g];
        }
      }
    }
  }
}

// ---------------- reduce partial mins -> col0 = sqrt(clip(min)) ----------------
__global__ void k_colmin(const float* __restrict__ pmin, float* __restrict__ col0){
  __shared__ float red[256];
  const int t = threadIdx.x;
  const int m0 = blockIdx.x * 64;
  const int m = m0 + (t & 63);
  const int g = t >> 6;
  float v = INFV;
  for (int b = g; b < 1563; b += 4) v = fminf(v, pmin[(size_t)b*832 + m]);
  red[t] = v;
  __syncthreads();
  if (t < 64){
    float vv = fminf(fminf(red[t], red[64+t]), fminf(red[128+t], red[192+t]));
    col0[m0 + t] = sqrtf(fmaxf(vv, 1e-12f));
  }
}

// ---------------- argmax row (first index) + 9th-smallest block-min threshold ----------------
__global__ void k_argmax(const float* __restrict__ col0,
                         const float* __restrict__ pmin,
                         float* __restrict__ scal){
  __shared__ float red[256];
  __shared__ int redi[256];
  __shared__ float cand[1563];
  const int t = threadIdx.x;

  float best = -INFV; int bi = 0x7FFFFFFF;
  for (int m = t; m < 784; m += 256){
    float v = col0[m];
    if (v > best){ best = v; bi = m; }
  }
  red[t] = best; redi[t] = bi;
  __syncthreads();
  for (int s = 128; s > 0; s >>= 1){
    if (t < s){
      if (red[t+s] > red[t] || (red[t+s] == red[t] && redi[t+s] < redi[t])){
        red[t] = red[t+s]; redi[t] = redi[t+s];
      }
    }
    __syncthreads();
  }
  const int r = redi[0];
  const float maxv = red[0];
  __syncthreads();

  for (int b = t; b < 1563; b += 256) cand[b] = pmin[(size_t)b*832 + r];
  __syncthreads();

  float b9 = 0.f;
  for (int it = 0; it < 9; ++it){
    float lb = INFV; int li = -1;
    for (int b = t; b < 1563; b += 256){
      float v = cand[b];
      if (v < lb){ lb = v; li = b; }
    }
    red[t] = lb; redi[t] = li;
    __syncthreads();
    for (int s = 128; s > 0; s >>= 1){
      if (t < s && red[t+s] < red[t]){ red[t] = red[t+s]; redi[t] = redi[t+s]; }
      __syncthreads();
    }
    b9 = red[0];
    if (t == 0 && redi[0] >= 0) cand[redi[0]] = INFV;
    __syncthreads();
  }
  if (t == 0){
    ((int*)scal)[0] = r;
    scal[1] = maxv;
    scal[2] = b9 + 1.0f;   // margin >> bf16-dot error bound
  }
}

// ---------------- recompute candidate blocks' distances for row r ----------------
__global__ void k_cand(const float* __restrict__ bank,
                       const unsigned short* __restrict__ Aw,
                       const float* __restrict__ en2,
                       const float* __restrict__ pmin,
                       const float* __restrict__ scal,
                       float* __restrict__ d2row){
  const int bid = blockIdx.x;
  const int t = threadIdx.x;
  const int r = ((const int*)scal)[0];
  const float thr = scal[2];
  const int n0 = bid * 64;

  if (pmin[(size_t)bid*832 + r] > thr){
    if (t < 64) d2row[n0 + t] = INFV;
    return;
  }
  __shared__ short er[1536];
  for (int k = t; k < 1536; k += 256){
    const int chunk = k >> 5, kq = (k >> 3) & 3, j = k & 7;
    er[k] = Aw[(size_t)chunk*26624 + (size_t)(kq*832 + r)*8 + j];
  }
  __syncthreads();
  const float e2r = en2[r];
  const int wv = t >> 6, ln = t & 63;
  for (int i = 0; i < 16; ++i){
    const int nl = wv*16 + i;
    const int n = n0 + nl;
    float dot = 0.f, b2 = 0.f;
    if (n < 100000){
      const float* bp2 = bank + (size_t)n * 1536;
      for (int k = ln; k < 1536; k += 64){
        float b = bp2[k];
        b2 += b*b;
        dot += bf2f(er[k]) * bf2f(f2bf(b));   // match pass-1 rounding
      }
    }
    #pragma unroll
    for (int off = 1; off < 64; off <<= 1){
      dot += __shfl_xor(dot, off, 64);
      b2  += __shfl_xor(b2,  off, 64);
    }
    if (ln == 0) d2row[n] = (n < 100000) ? (e2r + b2 - 2.0f*dot) : INFV;
  }
}

// ---------------- top-9 of d2row -> softmax weight -> score ----------------
__global__ void k_score(const float* __restrict__ d2row,
                        const float* __restrict__ scal,
                        float* __restrict__ outs){
  __shared__ float cs[2304];
  __shared__ float red[256];
  __shared__ int redi[256];
  __shared__ float nine[9];
  const int t = threadIdx.x;
  float loc[9];
  #pragma unroll
  for (int q = 0; q < 9; ++q) loc[q] = INFV;
  for (int n = t; n < 100000; n += 256){
    float v = d2row[n];
    if (v < loc[8]){
      loc[8] = v;
      #pragma unroll
      for (int q = 8; q > 0; --q){
        float a = fminf(loc[q-1], loc[q]);
        float b = fmaxf(loc[q-1], loc[q]);
        loc[q-1] = a; loc[q] = b;
      }
    }
  }
  #pragma unroll
  for (int q = 0; q < 9; ++q) cs[t*9 + q] = loc[q];
  __syncthreads();
  for (int it = 0; it < 9; ++it){
    float lb = INFV; int li = -1;
    for (int jx = t; jx < 2304; jx += 256){
      float v = cs[jx];
      if (v < lb){ lb = v; li = jx; }
    }
    red[t] = lb; redi[t] = li;
    __syncthreads();
    for (int s = 128; s > 0; s >>= 1){
      if (t < s && red[t+s] < red[t]){ red[t] = red[t+s]; redi[t] = redi[t+s]; }
      __syncthreads();
    }
    if (t == 0){ nine[it] = red[0]; if (redi[0] >= 0) cs[redi[0]] = INFV; }
    __syncthreads();
  }
  if (t == 0){
    float s[9];
    #pragma unroll
    for (int q = 0; q < 9; ++q) s[q] = sqrtf(fmaxf(nine[q], 1e-12f));
    const float mx = s[8];          // largest of the 9 scores
    float sum = 0.f;
    #pragma unroll
    for (int q = 0; q < 9; ++q) sum += expf(s[q] - mx);
    const float weight = 1.0f - 1.0f/sum;   // 1 - max(e)/sum(e), overflow-safe
    outs[0] = weight * scal[1];
  }
}

// ---------------- bilinear 28->224 (half-pixel, edge clamp) + vertical gaussian ----------------
__global__ void k_vblur(const float* __restrict__ col0, float* __restrict__ vmap){
  __shared__ float am[784];
  __shared__ float kw[33];
  const int t = threadIdx.x;
  for (int q = t; q < 784; q += 256) am[q] = col0[q];
  if (t < 33){ float d = (float)t - 16.0f; kw[t] = expf(-d*d*(1.0f/32.0f)); }
  __syncthreads();
  if (t == 0){
    float ss = 0.f;
    for (int q = 0; q < 33; ++q) ss += kw[q];
    const float inv = 1.0f/ss;
    for (int q = 0; q < 33; ++q) kw[q] *= inv;
  }
  __syncthreads();
  const int id = blockIdx.x*256 + t;
  const int i = id / 224, j = id % 224;
  const float ux = (j + 0.5f)*0.125f - 0.5f;
  const float fx0 = floorf(ux);
  const float fx = ux - fx0;
  int x0 = (int)fx0; int x1 = x0 + 1;
  x0 = max(0, min(27, x0)); x1 = max(0, min(27, x1));
  float a = 0.f;
  for (int d = 0; d < 33; ++d){
    int ii = i + d - 16;                         // symmetric pad
    ii = (ii < 0) ? (-1 - ii) : ((ii > 223) ? (447 - ii) : ii);
    const float uy = (ii + 0.5f)*0.125f - 0.5f;
    const float fy0 = floorf(uy);
    const float fy = uy - fy0;
    int y0 = (int)fy0; int y1 = y0 + 1;
    y0 = max(0, min(27, y0)); y1 = max(0, min(27, y1));
    const float top = (1.0f - fx)*am[y0*28 + x0] + fx*am[y0*28 + x1];
    const float bot = (1.0f - fx)*am[y1*28 + x0] + fx*am[y1*28 + x1];
    a += kw[d]*((1.0f - fy)*top + fy*bot);
  }
  vmap[id] = a;
}

// ---------------- horizontal gaussian (symmetric pad) ----------------
__global__ void k_hblur(const float* __restrict__ vmap, float* __restrict__ outm){
  __shared__ float rowb[256];
  __shared__ float kw[33];
  const int i = blockIdx.x;
  const int t = threadIdx.x;
  if (t < 33){ float d = (float)t - 16.0f; kw[t] = expf(-d*d*(1.0f/32.0f)); }
  __syncthreads();
  if (t == 0){
    float ss = 0.f;
    for (int q = 0; q < 33; ++q) ss += kw[q];
    const float inv = 1.0f/ss;
    for (int q = 0; q < 33; ++q) kw[q] *= inv;
  }
  int c = t - 16;
  c = (c < 0) ? (-1 - c) : ((c > 223) ? (447 - c) : c);
  rowb[t] = vmap[i*224 + c];
  __syncthreads();
  if (t < 224){
    float a = 0.f;
    #pragma unroll
    for (int d = 0; d < 33; ++d) a += kw[d]*rowb[t + d];
    outm[i*224 + t] = a;
  }
}

extern "C" void kernel_launch(void* const* d_in, const int* in_sizes, int n_in,
                              void* d_out, int out_size, void* d_ws, size_t ws_size,
                              hipStream_t stream) {
  const float* f2   = (const float*)d_in[0];   // 1x512x28x28
  const float* f3   = (const float*)d_in[1];   // 1x1024x14x14
  const float* bank = (const float*)d_in[2];   // 100000x1536
  float* out = (float*)d_out;                  // 50176 map + 1 score

  char* ws = (char*)d_ws;
  size_t off = 0;
  auto alloc = [&](size_t bytes) -> void* {
    void* p = ws + off;
    off += (bytes + 255) & ~(size_t)255;
    return p;
  };
  float* pf2           = (float*)alloc((size_t)512*784*4);
  float* pf3           = (float*)alloc((size_t)1024*196*4);
  unsigned short* A_ws = (unsigned short*)alloc((size_t)48*26624*2);
  float* en2           = (float*)alloc(832*4);
  float* pmin          = (float*)alloc((size_t)1563*832*4);
  float* col0          = (float*)alloc(832*4);
  float* scal          = (float*)alloc(64);
  float* d2row         = (float*)alloc(100032*4);
  float* vmap          = (float*)alloc((size_t)50176*4);

  k_pool  <<<2352, 256, 0, stream>>>(f2, f3, pf2, pf3);
  k_emb   <<<832,  256, 0, stream>>>(pf2, pf3, A_ws, en2);
  k_gemm  <<<1563, 768, 0, stream>>>(bank, A_ws, en2, pmin);
  k_colmin<<<13,   256, 0, stream>>>(pmin, col0);
  k_argmax<<<1,    256, 0, stream>>>(col0, pmin, scal);
  k_cand  <<<1563, 256, 0, stream>>>(bank, A_ws, en2, pmin, scal, d2row);
  k_score <<<1,    256, 0, stream>>>(d2row, scal, out + 50176);
  k_vblur <<<196,  256, 0, stream>>>(col0, vmap);
  k_hblur <<<224,  256, 0, stream>>>(vmap, out);
}